// Round 1
// baseline (1167.868 us; speedup 1.0000x reference)
//
#include <hip/hip_runtime.h>
#include <hip/hip_bf16.h>

#define TOKENS 16384
#define IN_F   4096
#define OUT_F  4096

typedef __attribute__((ext_vector_type(8))) _Float16 f16x8;
typedef __attribute__((ext_vector_type(4))) _Float16 f16x4;
typedef __attribute__((ext_vector_type(4))) float    f32x4;

// ---------------------------------------------------------------------------
// 1) global max|x| reduction -> ws[0] (as uint bits; positive-float monotonic)
// ---------------------------------------------------------------------------
__global__ __launch_bounds__(256) void maxabs_kernel(const float* __restrict__ x,
                                                     unsigned* __restrict__ out,
                                                     int n4) {
    const float4* x4 = (const float4*)x;
    int stride = gridDim.x * blockDim.x;
    float m = 0.f;
    for (int i = blockIdx.x * blockDim.x + threadIdx.x; i < n4; i += stride) {
        float4 v = x4[i];
        m = fmaxf(m, fmaxf(fmaxf(fabsf(v.x), fabsf(v.y)),
                           fmaxf(fabsf(v.z), fabsf(v.w))));
    }
    // wave64 reduce
    #pragma unroll
    for (int off = 32; off > 0; off >>= 1)
        m = fmaxf(m, __shfl_down(m, off));
    __shared__ float red[4];
    int lane = threadIdx.x & 63, w = threadIdx.x >> 6;
    if (lane == 0) red[w] = m;
    __syncthreads();
    if (threadIdx.x == 0) {
        m = fmaxf(fmaxf(red[0], red[1]), fmaxf(red[2], red[3]));
        atomicMax(out, __float_as_uint(m));
    }
}

// ---------------------------------------------------------------------------
// 2) dynamic int8 fake-quant of x, output fp16
//    scale = max(max|x|/127, 1e-8); xq = clip(rint(x/scale), -128, 127)*scale
// ---------------------------------------------------------------------------
__global__ __launch_bounds__(256) void quant_kernel(const float* __restrict__ x,
                                                    const unsigned* __restrict__ maxbits,
                                                    _Float16* __restrict__ xq,
                                                    int n4) {
    float mx = __uint_as_float(*maxbits);
    float scale = fmaxf(mx * (1.0f / 127.0f), 1e-8f);
    float inv = 1.0f / scale;
    const float4* x4 = (const float4*)x;
    int stride = gridDim.x * blockDim.x;
    for (int i = blockIdx.x * blockDim.x + threadIdx.x; i < n4; i += stride) {
        float4 v = x4[i];
        f16x4 h;
        h.x = (_Float16)(fminf(fmaxf(rintf(v.x * inv), -128.f), 127.f) * scale);
        h.y = (_Float16)(fminf(fmaxf(rintf(v.y * inv), -128.f), 127.f) * scale);
        h.z = (_Float16)(fminf(fmaxf(rintf(v.z * inv), -128.f), 127.f) * scale);
        h.w = (_Float16)(fminf(fmaxf(rintf(v.w * inv), -128.f), 127.f) * scale);
        *(f16x4*)(&xq[(size_t)i * 4]) = h;
    }
}

// ---------------------------------------------------------------------------
// 3) weight dequant: packed byte b -> elems {2b: high nibble, 2b+1: low}
//    group g = (2b)>>7 = b>>6; w = scale[g]*(nibble - zero[g]); output fp16 [N][K]
// ---------------------------------------------------------------------------
__global__ __launch_bounds__(256) void wdq_kernel(const int* __restrict__ packed,
                                                  const float* __restrict__ scales,
                                                  const float* __restrict__ zeros,
                                                  _Float16* __restrict__ w,
                                                  int n4) {
    const int4* p4 = (const int4*)packed;
    int stride = gridDim.x * blockDim.x;
    for (int i = blockIdx.x * blockDim.x + threadIdx.x; i < n4; i += stride) {
        int4 p = p4[i];
        int b0 = i * 4;
        int vals[4] = {p.x, p.y, p.z, p.w};
        f16x8 h;
        #pragma unroll
        for (int j = 0; j < 4; ++j) {
            int b = b0 + j;
            int g = b >> 6;
            float s = scales[g];
            float z = zeros[g];
            int v = vals[j];
            h[2 * j]     = (_Float16)(s * ((float)(v >> 4) - z));
            h[2 * j + 1] = (_Float16)(s * ((float)(v & 15) - z));
        }
        *(f16x8*)(&w[(size_t)i * 8]) = h;
    }
}

// ---------------------------------------------------------------------------
// 4) GEMM: C[M][N] = A[M][K] * B[N][K]^T, fp16 in / fp32 out
//    128x128 tile, BK=32, 256 threads (4 waves, 2x2), 16x16x32 MFMA, 4x4 frags
//    reg-staged LDS (single buffer, 2 barriers per K-step) — m97-family structure
// ---------------------------------------------------------------------------
__global__ __launch_bounds__(256, 2) void gemm_kernel(const _Float16* __restrict__ A,
                                                      const _Float16* __restrict__ B,
                                                      float* __restrict__ C) {
    const int M = TOKENS, N = OUT_F, K = IN_F;
    __shared__ __align__(16) _Float16 As[128 * 32];
    __shared__ __align__(16) _Float16 Bs[128 * 32];

    int bid = blockIdx.x;
    int bn = bid & 31;            // N/128 = 32
    int bm = bid >> 5;            // M/128 = 128
    int m0 = bm * 128, n0 = bn * 128;

    int tid = threadIdx.x;
    int lane = tid & 63, wid = tid >> 6;
    int wm = wid >> 1, wn = wid & 1;

    // staging: thread covers 8 fp16 of row r0 (j=0) and row r0+64 (j=1)
    int r0 = tid >> 2;            // 0..63
    int kk = (tid & 3) * 8;       // 0,8,16,24
    const _Float16* ga = A + (size_t)(m0 + r0) * K + kk;
    const _Float16* gb = B + (size_t)(n0 + r0) * K + kk;
    _Float16* sa = As + r0 * 32 + kk;
    _Float16* sb = Bs + r0 * 32 + kk;

    // fragment read base: row = l&15 (+16*frag), kgrp = l>>4 (8 consecutive k)
    int frow = lane & 15;
    int kgrp = lane >> 4;
    const _Float16* la = As + (wm * 64 + frow) * 32 + kgrp * 8;
    const _Float16* lb = Bs + (wn * 64 + frow) * 32 + kgrp * 8;

    f32x4 acc[4][4] = {};

    uint4 ra0 = *(const uint4*)(ga);
    uint4 ra1 = *(const uint4*)(ga + (size_t)64 * K);
    uint4 rb0 = *(const uint4*)(gb);
    uint4 rb1 = *(const uint4*)(gb + (size_t)64 * K);

    const int KT = K / 32;  // 128
    for (int kt = 0; kt < KT; ++kt) {
        *(uint4*)(sa)           = ra0;
        *(uint4*)(sa + 64 * 32) = ra1;
        *(uint4*)(sb)           = rb0;
        *(uint4*)(sb + 64 * 32) = rb1;
        __syncthreads();

        if (kt + 1 < KT) {
            const _Float16* ga2 = ga + (kt + 1) * 32;
            const _Float16* gb2 = gb + (kt + 1) * 32;
            ra0 = *(const uint4*)(ga2);
            ra1 = *(const uint4*)(ga2 + (size_t)64 * K);
            rb0 = *(const uint4*)(gb2);
            rb1 = *(const uint4*)(gb2 + (size_t)64 * K);
        }

        f16x8 af[4], bf[4];
        #pragma unroll
        for (int i = 0; i < 4; ++i) {
            af[i] = *(const f16x8*)(la + i * 16 * 32);
            bf[i] = *(const f16x8*)(lb + i * 16 * 32);
        }
        #pragma unroll
        for (int mi = 0; mi < 4; ++mi)
            #pragma unroll
            for (int ni = 0; ni < 4; ++ni)
                acc[mi][ni] = __builtin_amdgcn_mfma_f32_16x16x32_f16(af[mi], bf[ni],
                                                                     acc[mi][ni], 0, 0, 0);
        __syncthreads();
    }

    // epilogue: C/D layout col = lane&15, row = (lane>>4)*4 + j  [m89]
    int crow0 = m0 + wm * 64 + (lane >> 4) * 4;
    int ccol0 = n0 + wn * 64 + (lane & 15);
    #pragma unroll
    for (int mi = 0; mi < 4; ++mi)
        #pragma unroll
        for (int ni = 0; ni < 4; ++ni)
            #pragma unroll
            for (int j = 0; j < 4; ++j) {
                int r = crow0 + mi * 16 + j;
                int c = ccol0 + ni * 16;
                C[(size_t)r * N + c] = acc[mi][ni][j];
            }
}

// ---------------------------------------------------------------------------
extern "C" void kernel_launch(void* const* d_in, const int* in_sizes, int n_in,
                              void* d_out, int out_size, void* d_ws, size_t ws_size,
                              hipStream_t stream) {
    const float* x      = (const float*)d_in[0];
    const int*   packed = (const int*)d_in[1];
    const float* scales = (const float*)d_in[2];
    const float* zeros  = (const float*)d_in[3];
    float* out = (float*)d_out;

    unsigned* d_max = (unsigned*)d_ws;
    _Float16* d_xq  = (_Float16*)((char*)d_ws + 256);
    _Float16* d_wq  = (_Float16*)((char*)d_ws + 256 + (size_t)TOKENS * IN_F * 2);

    hipMemsetAsync(d_ws, 0, 4, stream);

    maxabs_kernel<<<2048, 256, 0, stream>>>(x, d_max, TOKENS * IN_F / 4);
    quant_kernel<<<2048, 256, 0, stream>>>(x, d_max, d_xq, TOKENS * IN_F / 4);
    wdq_kernel<<<2048, 256, 0, stream>>>(packed, scales, zeros, d_wq,
                                         OUT_F * IN_F / 2 / 4);

    dim3 grid((TOKENS / 128) * (OUT_F / 128));  // 4096 blocks
    gemm_kernel<<<grid, 256, 0, stream>>>(d_xq, d_wq, out);
}